// Round 3
// baseline (127.865 us; speedup 1.0000x reference)
//
#include <hip/hip_runtime.h>
#include <math.h>

#define NS2 0.70710678118654752440f  // 1/sqrt(2)
#define NS3 0.57735026918962576451f  // 1/sqrt(3)
#define NS6 0.40824829046386301636f  // 1/sqrt(6)

typedef _Float16 f16;
typedef _Float16 f16x8 __attribute__((ext_vector_type(8)));
typedef float    f32x4 __attribute__((ext_vector_type(4)));

// ws layout: G_T tiled by k-eighth: [8][7][2816] f16 (315.4 KB total).
// Eighth e covers global k: A-part k in [e*1280, +1280) -> local j 0..1279,
// B-part k in [10240 + e*1536, +1536) -> local j 1280..2815.
#define EI 19712          // 7*2816 f16 per eighth

// ---------------------------------------------------------------------------
// prep: G_T build only. 352 blocks x 64 columns. 4 o-split threads per k
// (q = tid>>6), kl = tid&63. LDS: s_wo[1680] + s_red[4][64][8].
// ---------------------------------------------------------------------------
__global__ __launch_bounds__(256) void prep_kernel(
    const float* __restrict__ W3_0, const float* __restrict__ W3_1,
    const float* __restrict__ W3_2, const float* __restrict__ Wout,
    f16* __restrict__ wsh)
{
    __shared__ __align__(16) float smem[3728];
    float* s_wo  = smem;            // Wout 240x7
    float* s_red = smem + 1680;     // [4][64][8] partials
    const int tid = threadIdx.x;
    for (int i = tid; i < 1680; i += 256) s_wo[i] = Wout[i];
    __syncthreads();
    const int kl = tid & 63, q = tid >> 6;
    const int k  = blockIdx.x * 64 + kl;       // 0..22527
    float acc[7] = {0.f,0.f,0.f,0.f,0.f,0.f,0.f};
    if (k < 4096) {                            // P1  (L=64, quarter=16)
        const float* wr = W3_0 + (size_t)k * 64;
        #pragma unroll
        for (int oo = 0; oo < 16; oo += 4) {
            int o = q*16 + oo;
            float4 wv = *(const float4*)(wr + o);
            const float* w0 = s_wo + o * 7;
            #pragma unroll
            for (int kk = 0; kk < 7; ++kk)
                acc[kk] = fmaf(wv.x, w0[kk], fmaf(wv.y, w0[7+kk],
                          fmaf(wv.z, w0[14+kk], fmaf(wv.w, w0[21+kk], acc[kk]))));
        }
    } else if (k < 10240) {                    // P4  (L=32, quarter=8)
        int it = k >> 6, s = it - 64, m = s >> 5, a2 = s & 31, l = k & 63;
        const float* wr = W3_1 + (size_t)(2048 + a2*64 + l) * 32;
        #pragma unroll
        for (int oo = 0; oo < 8; oo += 4) {
            int o = q*8 + oo;
            float4 wv = *(const float4*)(wr + o);
            const float* w0 = s_wo + (64 + o*3 + m) * 7;
            #pragma unroll
            for (int kk = 0; kk < 7; ++kk)
                acc[kk] = fmaf(wv.x, w0[kk], fmaf(wv.y, w0[21+kk],
                          fmaf(wv.z, w0[42+kk], fmaf(wv.w, w0[63+kk], acc[kk]))));
        }
    } else {
        int it2 = (k - 10240) >> 5, l32 = k & 31;
        if (it2 < 32) {                        // P2  (L=64)
            const float* wr = W3_0 + (size_t)(4096 + it2*32 + l32) * 64;
            #pragma unroll
            for (int oo = 0; oo < 16; oo += 4) {
                int o = q*16 + oo;
                float4 wv = *(const float4*)(wr + o);
                const float* w0 = s_wo + o * 7;
                #pragma unroll
                for (int kk = 0; kk < 7; ++kk)
                    acc[kk] = fmaf(wv.x, w0[kk], fmaf(wv.y, w0[7+kk],
                              fmaf(wv.z, w0[14+kk], fmaf(wv.w, w0[21+kk], acc[kk]))));
            }
        } else if (it2 < 224) {                // P3  (L=32)
            int t = it2 - 32, m = t >> 6, a = t & 63;
            const float* wr = W3_1 + (size_t)(a*32 + l32) * 32;
            #pragma unroll
            for (int oo = 0; oo < 8; oo += 4) {
                int o = q*8 + oo;
                float4 wv = *(const float4*)(wr + o);
                const float* w0 = s_wo + (64 + o*3 + m) * 7;
                #pragma unroll
                for (int kk = 0; kk < 7; ++kk)
                    acc[kk] = fmaf(wv.x, w0[kk], fmaf(wv.y, w0[21+kk],
                              fmaf(wv.z, w0[42+kk], fmaf(wv.w, w0[63+kk], acc[kk]))));
            }
        } else {                               // P5  (L=16, quarter=4)
            int t = it2 - 224, m = t >> 5, a = t & 31;
            const float* wr = W3_2 + (size_t)(a*32 + l32) * 16;
            int o = q*4;
            float4 wv = *(const float4*)(wr + o);
            const float* w0 = s_wo + (160 + o*5 + m) * 7;
            #pragma unroll
            for (int kk = 0; kk < 7; ++kk)
                acc[kk] = fmaf(wv.x, w0[kk], fmaf(wv.y, w0[35+kk],
                          fmaf(wv.z, w0[70+kk], fmaf(wv.w, w0[105+kk], acc[kk]))));
        }
    }
    #pragma unroll
    for (int r = 0; r < 7; ++r) s_red[(q*64 + kl)*8 + r] = acc[r];
    __syncthreads();
    if (tid < 64) {
        int kk2 = blockIdx.x * 64 + tid;
        int e, j;
        if (kk2 < 10240) { e = kk2 / 1280; j = kk2 - e*1280; }
        else { int kb = kk2 - 10240; e = kb / 1536; j = 1280 + kb - e*1536; }
        f16* dst = wsh + e*EI + j;
        #pragma unroll
        for (int r = 0; r < 7; ++r) {
            float v = s_red[(      tid)*8 + r] + s_red[( 64 + tid)*8 + r]
                    + s_red[(128 + tid)*8 + r] + s_red[(192 + tid)*8 + r];
            dst[r*2816] = (f16)v;
        }
    }
}

// ---------------------------------------------------------------------------
// main: 256 blocks x 16 nodes, full K per block (waves split K).
// Per pass p (k-eighth): wave w computes A-chunks [w*10,+10) + B-chunks
// [40+w*12,+12) (22 of 88); 8 passes => 176 chunks/wave; 4-wave partials
// reduced in LDS; out = bias + sum (plain store, no atomics).
// LDS (93248 B, 1 block/CU):
//   [0]      s_g  [2][7][2832] f16  79296 B  (pad 2832: rows 8 banks apart)
//   [79296]  s_uv [16][216]    f16   6912 B  (a0|A1|b0|B1|geom|1.0)
//   [86208]  s_ugt[2][88][16]  f16   5632 B  (u*geom per chunk,node)
//   [91840]  s_idx[8][88]      u16   1408 B
//   overlays: s_f0[16][64]+s_f1[16][32] f32 (phase N, in s_g area);
//             s_part[4][16][8] f32 (epilogue, in s_g area)
// ---------------------------------------------------------------------------
__global__ __launch_bounds__(256, 1) void main_kernel(
    const f16* __restrict__ wsh,
    const float* __restrict__ pos,
    const float* __restrict__ W1_0, const float* __restrict__ W1_1,
    const float* __restrict__ W2_0, const float* __restrict__ W2_1,
    const float* __restrict__ bout,
    float* __restrict__ out, int N)
{
    __shared__ __align__(16) char smem[93248];
    f16* s_g   = (f16*)smem;                       // [2][7][2832]
    f16* s_uv  = (f16*)(smem + 79296);             // [16][216]
    f16* s_ugt = (f16*)(smem + 86208);             // [2][88][16]
    unsigned short* s_idx = (unsigned short*)(smem + 91840);
    float* s_f0 = (float*)smem;                    // [16][64] overlay
    float* s_f1 = (float*)(smem + 4096);           // [16][32] overlay
    (void)N;

    const int tid  = threadIdx.x;
    const int base = blockIdx.x * 16;

    // ---- phase N0: radial basis + geom + idx table ----
    {
        int d = tid & 63;
        #pragma unroll
        for (int it = 0; it < 4; ++it) {
            int n = (tid >> 6) + it*4;
            const float* pp = pos + (size_t)(base + n) * 3;
            float px = pp[0], py = pp[1], pz = pp[2];
            float r  = sqrtf(px*px + py*py + pz*pz) + 1e-9f;
            float t0 = r - (5.0f/63.0f) * (float)d;
            s_f0[n*64 + d] = __expf(-4.f * t0 * t0);
        }
        int d1 = tid & 31;
        #pragma unroll
        for (int it = 0; it < 2; ++it) {
            int n = (tid >> 5) + it*8;
            const float* pp = pos + (size_t)(base + n) * 3;
            float px = pp[0], py = pp[1], pz = pp[2];
            float r  = sqrtf(px*px + py*py + pz*pz) + 1e-9f;
            float t1 = r - (5.0f/31.0f) * (float)d1;
            s_f1[n*32 + d1] = __expf(-4.f * t1 * t1);
        }
        if (tid < 16) {
            const float* pp = pos + (size_t)(base + tid) * 3;
            float px = pp[0], py = pp[1], pz = pp[2];
            float r  = sqrtf(px*px + py*py + pz*pz) + 1e-9f;
            float iv = 1.0f / r;
            float d0 = py*iv, dz = pz*iv, dx = px*iv;       // (y,z,x)
            f16* row = s_uv + tid*216;
            row[192+0] = (f16)d0;
            row[192+1] = (f16)dz;
            row[192+2] = (f16)dx;
            row[192+3] = (f16)(NS3 * (d0*d0 + dz*dz + dx*dx));
            row[192+4] = (f16)(2.f*NS2*dx*d0);
            row[192+5] = (f16)(2.f*NS2*d0*dz);
            row[192+6] = (f16)(NS6*(2.f*dz*dz - dx*dx - d0*d0));
            row[192+7] = (f16)(2.f*NS2*dx*dz);
            row[192+8] = (f16)(NS2*(dx*dx - d0*d0));
            row[201]   = (f16)1.0f;
        }
        for (int c = tid; c < 704; c += 256) {      // s_idx, pass-major
            int p  = c / 88, cl = c - p*88;
            int gc = (cl < 40) ? p*40 + cl : 320 + p*48 + (cl - 40);
            int uidx, gidx;
            if (gc < 320) {
                int it = gc >> 1;
                if (it < 64) { uidx = it; gidx = 9; }
                else { int s = it - 64; uidx = 64 + (s & 31); gidx = s >> 5; }
            } else {
                int it2 = gc - 320;
                if (it2 < 32)       { uidx = 64 + it2;                  gidx = 3; }
                else if (it2 < 224) { int t = it2 - 32;  uidx = t & 63;         gidx = t >> 6; }
                else                { int t = it2 - 224; uidx = 64 + (t & 31);  gidx = 4 + (t >> 5); }
            }
            s_idx[c] = (unsigned short)(uidx | (gidx << 8));
        }
    }
    __syncthreads();

    // ---- phase N1: channel-mix GEMMs (fp32) -> s_uv f16 ----
    {
        int c = tid & 63, jb = tid >> 6;
        float a0a[4] = {0,0,0,0}, b0a[4] = {0,0,0,0};
        const float* wa = W1_0 + c;
        const float* wb = W2_0 + c;
        for (int d = 0; d < 64; ++d) {
            float wav = wa[d*64], wbv = wb[d*64];
            #pragma unroll
            for (int m = 0; m < 4; ++m) {
                float f = s_f0[(jb + 4*m)*64 + d];
                a0a[m] = fmaf(f, wav, a0a[m]);
                b0a[m] = fmaf(f, wbv, b0a[m]);
            }
        }
        #pragma unroll
        for (int m = 0; m < 4; ++m) {
            s_uv[(jb + 4*m)*216 +      c] = (f16)a0a[m];
            s_uv[(jb + 4*m)*216 + 96 + c] = (f16)b0a[m];
        }
        int c1 = tid & 31, j8 = tid >> 5;
        float Aa[2] = {0,0}, Ba[2] = {0,0};
        const float* wA = W1_1 + c1;
        const float* wB = W2_1 + c1;
        for (int d = 0; d < 32; ++d) {
            float wAv = wA[d*32], wBv = wB[d*32];
            #pragma unroll
            for (int m = 0; m < 2; ++m) {
                float f = s_f1[(j8 + 8*m)*32 + d];
                Aa[m] = fmaf(f, wAv, Aa[m]);
                Ba[m] = fmaf(f, wBv, Ba[m]);
            }
        }
        #pragma unroll
        for (int m = 0; m < 2; ++m) {
            s_uv[(j8 + 8*m)*216 +  64 + c1] = (f16)Aa[m];
            s_uv[(j8 + 8*m)*216 + 160 + c1] = (f16)Ba[m];
        }
    }
    __syncthreads();

    // ---- per-lane constants ----
    const int w    = tid >> 6;
    const int lane = tid & 63;
    const int lq   = lane >> 4;            // k-subrange quarter / D row-group
    const int lm   = lane & 15;            // A row (out-k) / B col (node)
    const int ra   = lm % 7;               // rows 7..15 duplicate (discarded)
    const f16* myrow = s_uv + lm*216;
    f16x8 vA0 = *(const f16x8*)(myrow +  96 + lq*8);   // b0[ 0..31]
    f16x8 vA1 = *(const f16x8*)(myrow + 128 + lq*8);   // b0[32..63]
    f16x8 vB  = *(const f16x8*)(myrow + 160 + lq*8);   // B1[ 0..31]

    // ---- staging helpers (T14: issue-early, write-late) ----
    uint4 rg[10];
    auto stage_load = [&](int p) {
        const uint4* src = (const uint4*)(wsh + p*EI);   // 39424 B contiguous
        #pragma unroll
        for (int it = 0; it < 10; ++it) {
            int j = tid + it*256;
            if (j < 2464) rg[it] = src[j];
        }
    };
    auto stage_write = [&](int buf) {
        f16* dst0 = s_g + buf*19824;
        #pragma unroll
        for (int it = 0; it < 10; ++it) {
            int j = tid + it*256;
            if (j < 2464) {
                int row = j / 352, col = j - row*352;
                *(uint4*)(dst0 + row*2832 + col*8) = rg[it];
            }
        }
    };
    auto do_ugt = [&](int p, int buf) {
        f16* dstu = s_ugt + buf*1408;
        #pragma unroll
        for (int it = 0; it < 6; ++it) {
            int j = tid + it*256;
            if (j < 1408) {
                int cl = j >> 4, n = j & 15;
                unsigned short ix = s_idx[p*88 + cl];
                float u  = (float)s_uv[n*216 + (ix & 255)];
                float gg = (float)s_uv[n*216 + 192 + (ix >> 8)];
                dstu[cl*16 + n] = (f16)(u * gg);
            }
        }
    };

    f32x4 acc0 = {0.f,0.f,0.f,0.f}, acc1 = {0.f,0.f,0.f,0.f};
    auto compute = [&](int buf) {
        const f16* gb = s_g + buf*19824 + ra*2832 + lq*8;
        const f16* ub = s_ugt + buf*1408;
        #pragma unroll
        for (int i = 0; i < 10; ++i) {                 // A chunks [w*10,+10)
            int c = w*10 + i;
            f16 ug  = ub[c*16 + lm];
            f16x8 a = *(const f16x8*)(gb + c*32);
            f16x8 vv = (i & 1) ? vA1 : vA0;            // chunk parity = i parity
            f16x8 b;
            #pragma unroll
            for (int j2 = 0; j2 < 8; ++j2) b[j2] = vv[j2] * ug;
            if (i & 1) acc1 = __builtin_amdgcn_mfma_f32_16x16x32_f16(a, b, acc1, 0, 0, 0);
            else       acc0 = __builtin_amdgcn_mfma_f32_16x16x32_f16(a, b, acc0, 0, 0, 0);
        }
        #pragma unroll
        for (int i = 0; i < 12; ++i) {                 // B chunks [40+w*12,+12)
            int c = 40 + w*12 + i;
            f16 ug  = ub[c*16 + lm];
            f16x8 a = *(const f16x8*)(gb + c*32);
            f16x8 b;
            #pragma unroll
            for (int j2 = 0; j2 < 8; ++j2) b[j2] = vB[j2] * ug;
            if (i & 1) acc1 = __builtin_amdgcn_mfma_f32_16x16x32_f16(a, b, acc1, 0, 0, 0);
            else       acc0 = __builtin_amdgcn_mfma_f32_16x16x32_f16(a, b, acc0, 0, 0, 0);
        }
    };

    // ---- 8-pass double-buffered pipeline ----
    stage_load(0); stage_write(0); do_ugt(0, 0);
    __syncthreads();
    for (int p = 0; p < 8; ++p) {
        int buf = p & 1;
        if (p < 7) { stage_load(p + 1); do_ugt(p + 1, buf ^ 1); }
        compute(buf);
        if (p < 7) stage_write(buf ^ 1);
        __syncthreads();
    }

    // ---- cross-wave reduce + plain store (bias included) ----
    float* s_part = (float*)smem;                      // [4][16][8] overlay
    if (lq < 2) {
        int nr = (lq == 0) ? 4 : 3;
        for (int r = 0; r < nr; ++r)
            s_part[(w*16 + lm)*8 + lq*4 + r] = acc0[r] + acc1[r];
    }
    __syncthreads();
    if (tid < 112) {
        int n = tid / 7, r = tid - n*7;
        float v = bout[r];
        #pragma unroll
        for (int ww = 0; ww < 4; ++ww) v += s_part[(ww*16 + n)*8 + r];
        out[(size_t)(base + n)*7 + r] = v;
    }
}

extern "C" void kernel_launch(void* const* d_in, const int* in_sizes, int n_in,
                              void* d_out, int out_size, void* d_ws, size_t ws_size,
                              hipStream_t stream)
{
    const float* pos  = (const float*)d_in[0];
    const float* W1_0 = (const float*)d_in[1];
    const float* W1_1 = (const float*)d_in[2];
    const float* W2_0 = (const float*)d_in[3];
    const float* W2_1 = (const float*)d_in[4];
    const float* W3_0 = (const float*)d_in[5];
    const float* W3_1 = (const float*)d_in[6];
    const float* W3_2 = (const float*)d_in[7];
    const float* Wout = (const float*)d_in[8];
    const float* bout = (const float*)d_in[9];
    f16*   wsh = (f16*)d_ws;
    float* op  = (float*)d_out;
    int N = in_sizes[0] / 3;   // 4096

    prep_kernel<<<352, 256, 0, stream>>>(W3_0, W3_1, W3_2, Wout, wsh);
    main_kernel<<<256, 256, 0, stream>>>(wsh, pos, W1_0, W1_1, W2_0, W2_1,
                                         bout, op, N);
}